// Round 15
// baseline (191.653 us; speedup 1.0000x reference)
//
#include <hip/hip_runtime.h>
#include <hip/hip_bf16.h>
#include <math.h>

#define BN 4096   // batch per domain
#define DD 256    // feature dim
#define CC 31     // label classes
#define KP 352    // packed k per row: 256 feat + 32 augA + 32 augB + 32 label
#define AUGA 256
#define AUGB 288
#define LABK 320
#define LROW 40   // LDS row pitch in shorts (80 B)

typedef __attribute__((ext_vector_type(8))) short bf16x8;
typedef __attribute__((ext_vector_type(16))) float f32x16;

static __device__ inline unsigned short f2bf(float v) {
  __hip_bfloat16 h = __float2bfloat16(v);
  union { __hip_bfloat16 h; unsigned short u; } cv;
  cv.h = h;
  return cv.u;
}
static __device__ inline float bf2f(unsigned short u) {
  return __uint_as_float(((unsigned int)u) << 16);
}

// ---------------- workspace layout ----------------
// [0]        double loss_acc
// [1]        double sum_sq
// [2..257]   double colsum[256]
// [258..289] double labsumS[32]
// [290..321] double labsumT[32]
// byte 2624: float aScale[32], bScale[32], negc[8]
// byte 4096: unsigned short pack[8192][352]   (~5.8 MB)

// ---------------- fused stats: feature colsums + sumsq + label colsums --------
__global__ void stats_kernel(const float* __restrict__ source,
                             const float* __restrict__ target,
                             const float* __restrict__ s_label,
                             const float* __restrict__ t_label,
                             double* __restrict__ colsum,
                             double* __restrict__ sumsq,
                             double* __restrict__ labsumS,
                             double* __restrict__ labsumT) {
  const int d = threadIdx.x;
  const int r0 = blockIdx.x * 32;
  float cs = 0.f, sq = 0.f;
  for (int r = r0; r < r0 + 32; ++r) {
    const float v = (r < BN) ? source[(size_t)r * DD + d]
                             : target[(size_t)(r - BN) * DD + d];
    cs += v;
    sq += v * v;
  }
  atomicAdd(&colsum[d], (double)cs);
  __shared__ float red[256];
  red[d] = sq;
  __syncthreads();
  for (int s = 128; s; s >>= 1) {
    if (d < s) red[d] += red[d + s];
    __syncthreads();
  }
  if (d == 0) atomicAdd(sumsq, (double)red[0]);

  if (d < CC) {
    const bool isS = (blockIdx.x < 128);
    const int lr0 = (isS ? blockIdx.x : blockIdx.x - 128) * 32;
    const float* lab = isS ? s_label : t_label;
    float ls = 0.f;
    for (int r = lr0; r < lr0 + 32; ++r) ls += lab[(size_t)r * CC + d];
    atomicAdd(isS ? &labsumS[d] : &labsumT[d], (double)ls);
  }
}

// ---------------- bw + scales: one block ----------------
__global__ void bw_scale_kernel(const double* __restrict__ sumsq,
                                const double* __restrict__ colsum,
                                const double* __restrict__ labsumS,
                                const double* __restrict__ labsumT,
                                float* __restrict__ negc,
                                float* __restrict__ aScale,
                                float* __restrict__ bScale) {
  __shared__ double red[256];
  int t = threadIdx.x;
  double cs = colsum[t];
  red[t] = cs * cs;
  __syncthreads();
  for (int s = 128; s; s >>= 1) {
    if (t < s) red[t] += red[t + s];
    __syncthreads();
  }
  if (t == 0) {
    double suml2 = 2.0 * 8192.0 * (*sumsq) - 2.0 * red[0];
    double bw = suml2 / (8192.0 * 8192.0 - 8192.0);
    bw = bw / 4.0;  // KERNEL_MUL^(KERNEL_NUM//2)
    for (int k = 0; k < 5; ++k)
      negc[k] = (float)(-1.0 / (bw * (double)(1 << k)));
  }
  if (t < 32) {
    double s_sum = (t < CC) ? labsumS[t] : 0.0;
    double t_sum = (t < CC) ? labsumT[t] : 0.0;
    bool valid = (t < CC) && (s_sum != 0.0) && (t_sum != 0.0);
    aScale[t] = valid ? (float)(1.0 / s_sum) : 0.f;
    bScale[t] = valid ? (float)(1.0 / t_sum) : 0.f;
  }
}

// ---------------- pack kernel: fp32 -> bf16 rows with aug + labels ----------------
__global__ void pack_kernel(const float* __restrict__ source,
                            const float* __restrict__ target,
                            const float* __restrict__ s_label,
                            const float* __restrict__ t_label,
                            const float* __restrict__ aScale,
                            const float* __restrict__ bScale,
                            unsigned short* __restrict__ pack) {
  const int vr = blockIdx.x * 4 + (threadIdx.x >> 6);  // 0..8191
  const int l = threadIdx.x & 63;
  const bool isS = (vr < BN);
  const float* xp = isS ? (source + (size_t)vr * DD)
                        : (target + (size_t)(vr - BN) * DD);
  float4 v = ((const float4*)xp)[l];
  unsigned short ub[4] = {f2bf(v.x), f2bf(v.y), f2bf(v.z), f2bf(v.w)};
  float f[4];
#pragma unroll
  for (int e = 0; e < 4; ++e) f[e] = bf2f(ub[e]);
  float sq = f[0] * f[0] + f[1] * f[1] + f[2] * f[2] + f[3] * f[3];
#pragma unroll
  for (int off = 32; off; off >>= 1) sq += __shfl_xor(sq, off);

  const size_t rb = (size_t)vr * KP;
  *(short4*)&pack[rb + l * 4] =
      make_short4((short)ub[0], (short)ub[1], (short)ub[2], (short)ub[3]);

  if (l < 8) {
    const unsigned short one = f2bf(1.0f);
    const float hs = -0.5f * sq;
    const unsigned short hh = f2bf(hs);
    const unsigned short lo = f2bf(hs - bf2f(hh));
    const int c0 = l * 4;
    unsigned short a_aug[4], b_aug[4], labv[4];
#pragma unroll
    for (int e = 0; e < 4; ++e) {
      const int c = c0 + e;
      a_aug[e] = (c == 0) ? hh : (c == 1) ? lo : (c <= 3) ? one : (unsigned short)0;
      b_aug[e] = (c <= 1) ? one : (c == 2) ? hh : (c == 3) ? lo : (unsigned short)0;
      float lv = 0.f;
      if (c < CC) {
        lv = isS ? s_label[(size_t)vr * CC + c] * aScale[c]
                 : t_label[(size_t)(vr - BN) * CC + c] * bScale[c];
      }
      labv[e] = f2bf(lv);
    }
    *(short4*)&pack[rb + AUGA + c0] = make_short4(
        (short)a_aug[0], (short)a_aug[1], (short)a_aug[2], (short)a_aug[3]);
    *(short4*)&pack[rb + AUGB + c0] = make_short4(
        (short)b_aug[0], (short)b_aug[1], (short)b_aug[2], (short)b_aug[3]);
    *(short4*)&pack[rb + LABK + c0] = make_short4(
        (short)labv[0], (short)labv[1], (short)labv[2], (short)labv[3]);
  }
}

// ---------------- main fused kernel (32x32x16 MFMA + LDS-staged B) -----------
// 64x64 tile per block; 4 waves in a 2x2 grid of 32x32 tiles.
// Per chunk (K=32 = 2 ksteps of 16): wave reads 4 b128 from LDS (B S+T x 2 ks)
// vs 8 with 16x16 shape -> halves the LDS-read bytes per FLOP (the measured
// bottleneck: ~71 B/cyc/CU demand vs ~85 achievable). A from global (L2).
__global__ __launch_bounds__(256) void lmmd_main(
    const unsigned short* __restrict__ pack, const float* __restrict__ negc,
    double* __restrict__ accOut) {
  __shared__ __align__(16) unsigned short bufB[2][128][LROW];  // 20 KB
  __shared__ double dred[256];

  const int t = threadIdx.x;
  const int lane = t & 63;
  const int wv = t >> 6;
  const int wr = wv >> 1;        // row-group 0..1
  const int wc = wv & 1;         // col-group 0..1
  const int bi = blockIdx.x >> 6;
  const int bj = blockIdx.x & 63;
  const int r31 = lane & 31;
  const int kh = (lane >> 5) * 8;  // k-half offset (shorts) within a kstep

  const int rowSi = (bi * 64 + wr * 32 + r31) * KP;  // A: S row
  const int rowTi = rowSi + BN * KP;                 // A: T row
  const int pcS = wc * 32 + r31;        // LDS panel row for S col
  const int pcT = 64 + wc * 32 + r31;   // LDS panel row for T col

  // staging assignment: thread t stages 32 B of the 8 KB chunk panel
  const int srow = t >> 1;                       // 0..127 (0-63 S, 64-127 T)
  const int soff = (t & 1) * 16;                 // short offset within row
  const int srowG = (srow < 64) ? (bj * 64 + srow) : (BN + bj * 64 + (srow - 64));
  const size_t sbase = (size_t)srowG * KP;

  constexpr int koAarr[10] = {0, 32, 64, 96, 128, 160, 192, 224, AUGA, LABK};
  constexpr int koBarr[10] = {0, 32, 64, 96, 128, 160, 192, 224, AUGB, LABK};

  f32x16 aSS = {}, aTT = {}, aST = {}, wSS = {}, wTT = {}, wST = {};

  // prologue: stage chunk 0 into buf 0
  {
    const float4 v0 = *(const float4*)&pack[sbase + koBarr[0] + soff];
    const float4 v1 = *(const float4*)&pack[sbase + koBarr[0] + soff + 8];
    *(float4*)&bufB[0][srow][soff] = v0;
    *(float4*)&bufB[0][srow][soff + 8] = v1;
  }

#pragma unroll
  for (int c = 0; c < 10; ++c) {
    __syncthreads();  // buf[c&1] ready; all reads of buf[(c+1)&1] from c-1 done
    // issue-early: global loads for next chunk's staging
    float4 s0, s1;
    if (c < 9) {
      s0 = *(const float4*)&pack[sbase + koBarr[c + 1] + soff];
      s1 = *(const float4*)&pack[sbase + koBarr[c + 1] + soff + 8];
    }
    const int cb = c & 1;
#pragma unroll
    for (int ks = 0; ks < 2; ++ks) {
      const int koA = koAarr[c] + ks * 16 + kh;
      const int koL = ks * 16 + kh;
      const bf16x8 aS = *(const bf16x8*)&pack[rowSi + koA];
      const bf16x8 aT = *(const bf16x8*)&pack[rowTi + koA];
      const bf16x8 bS = *(const bf16x8*)&bufB[cb][pcS][koL];
      const bf16x8 bT = *(const bf16x8*)&bufB[cb][pcT][koL];
      if (c < 9) {
        aSS = __builtin_amdgcn_mfma_f32_32x32x16_bf16(aS, bS, aSS, 0, 0, 0);
        aTT = __builtin_amdgcn_mfma_f32_32x32x16_bf16(aT, bT, aTT, 0, 0, 0);
        aST = __builtin_amdgcn_mfma_f32_32x32x16_bf16(aS, bT, aST, 0, 0, 0);
      } else {
        wSS = __builtin_amdgcn_mfma_f32_32x32x16_bf16(aS, bS, wSS, 0, 0, 0);
        wTT = __builtin_amdgcn_mfma_f32_32x32x16_bf16(aT, bT, wTT, 0, 0, 0);
        wST = __builtin_amdgcn_mfma_f32_32x32x16_bf16(aS, bT, wST, 0, 0, 0);
      }
    }
    // write-late: stage next chunk into the other buffer
    if (c < 9) {
      const int nb = (c + 1) & 1;
      *(float4*)&bufB[nb][srow][soff] = s0;
      *(float4*)&bufB[nb][srow][soff + 8] = s1;
    }
  }

  // epilogue: l2 = -2*acc, 5-kernel exp sum, weighted combine (all co-located;
  // layout-invariant: elementwise on identically-shaped MFMA outputs)
  const float nc0 = negc[0], nc1 = negc[1], nc2 = negc[2], nc3 = negc[3],
              nc4 = negc[4];
  double tsum = 0.0;
#pragma unroll
  for (int e = 0; e < 16; ++e) {
    const float l2ss = -2.f * aSS[e];
    const float l2tt = -2.f * aTT[e];
    const float l2st = -2.f * aST[e];
    const float Kss = __expf(l2ss * nc0) + __expf(l2ss * nc1) +
                      __expf(l2ss * nc2) + __expf(l2ss * nc3) +
                      __expf(l2ss * nc4);
    const float Ktt = __expf(l2tt * nc0) + __expf(l2tt * nc1) +
                      __expf(l2tt * nc2) + __expf(l2tt * nc3) +
                      __expf(l2tt * nc4);
    const float Kst = __expf(l2st * nc0) + __expf(l2st * nc1) +
                      __expf(l2st * nc2) + __expf(l2st * nc3) +
                      __expf(l2st * nc4);
    tsum += (double)(wSS[e] * Kss + wTT[e] * Ktt - 2.f * wST[e] * Kst);
  }
  dred[t] = tsum;
  __syncthreads();
  for (int s = 128; s; s >>= 1) {
    if (t < s) dred[t] += dred[t + s];
    __syncthreads();
  }
  if (t == 0) atomicAdd(accOut, dred[0]);
}

// ---------------- finalize ----------------
__global__ void finalize_kernel(const double* __restrict__ acc,
                                float* __restrict__ out) {
  out[0] = (float)acc[0];
}

extern "C" void kernel_launch(void* const* d_in, const int* in_sizes, int n_in,
                              void* d_out, int out_size, void* d_ws,
                              size_t ws_size, hipStream_t stream) {
  const float* source = (const float*)d_in[0];
  const float* target = (const float*)d_in[1];
  const float* s_label = (const float*)d_in[2];
  const float* t_label = (const float*)d_in[3];

  double* acc = (double*)d_ws;   // [0] loss
  double* sumsq = acc + 1;       // [1]
  double* colsum = acc + 2;      // [2..257]
  double* labsumS = acc + 258;   // [258..289]
  double* labsumT = acc + 290;   // [290..321]
  float* fbase = (float*)((char*)d_ws + 2624);
  float* aScale = fbase;         // 32
  float* bScale = fbase + 32;    // 32
  float* negc = fbase + 64;      // 8
  unsigned short* pack = (unsigned short*)((char*)d_ws + 4096);  // 8192*352

  hipMemsetAsync(d_ws, 0, 2624, stream);
  stats_kernel<<<256, 256, 0, stream>>>(source, target, s_label, t_label,
                                        colsum, sumsq, labsumS, labsumT);
  bw_scale_kernel<<<1, 256, 0, stream>>>(sumsq, colsum, labsumS, labsumT,
                                         negc, aScale, bScale);
  pack_kernel<<<2048, 256, 0, stream>>>(source, target, s_label, t_label,
                                        aScale, bScale, pack);
  lmmd_main<<<4096, 256, 0, stream>>>(pack, negc, acc);
  finalize_kernel<<<1, 1, 0, stream>>>(acc, (float*)d_out);
}